// Round 4
// baseline (378.400 us; speedup 1.0000x reference)
//
#include <hip/hip_runtime.h>
#include <stdint.h>

#define D_DIM 1024
#define M_DIM 128
#define BR 32
#define BD 32
#define NCHUNK (D_DIM / BD)   // 32

// Bit-exact semantics (verified R7, absmax=0.0):
//   h[r][m]  = sequential __fmaf_rn chain over d = 0..1023 (ascending)
//   FWHT stages on column-bit 0,1,...,6 ascending; out[bit]=a+b / a-b, fp32
//   bit = (h > 0) ? 1.0f : 0.0f
//
// R11: TLP back. 4x4 per-thread tile -> 4096 waves -> 16 waves/CU =
//   4 waves/SIMD (R9/R10's 8x8 tile structurally capped at 1/SIMD and
//   exposed every latency gap). 256-thr blocks (32 col-quads x 8 row
//   groups), BR=32, grid=1024 = exactly 4 blocks/CU.
//   - X stays global-direct (2 unique addrs/instr, L1 broadcast); all
//     in-loop X offsets are compile-time immediates -> no address VALU.
//   - W LDS double-buffer 2x16KB via global_load_lds; chunk-XOR swizzle
//     phys = cj ^ ((row>>2)&7) applied on the GLOBAL source (linear DMA
//     dest) and re-applied on the read -> 4 addrs/bank-quad = the
//     4-round data floor for a 32-unique-address ds_read_b128.
//   - launch_bounds(256,4) pins VGPR <= 128 so 4 blocks/CU co-reside.
//   Per j4 per wave: 4 ds_read + 4 global + 64 FMA -> VALU is the
//   saturated pipe (LDS and TA each ~50%).

typedef const __attribute__((address_space(1))) void* gas_cptr;
typedef __attribute__((address_space(3))) void* lds_vptr;

__device__ __forceinline__ void gload_lds16(const float* g, float* l) {
    __builtin_amdgcn_global_load_lds((gas_cptr)g, (lds_vptr)l, 16, 0, 0);
}

__global__ __launch_bounds__(256, 4)
void rewa_kernel(const float* __restrict__ X, const float* __restrict__ W,
                 float* __restrict__ out) {
    #pragma clang fp contract(off)
    __shared__ float wsh[2][M_DIM * BD];   // 2 x 16 KB, chunk-swizzled

    const int t    = threadIdx.x;
    const int lane = t & 63;
    const int wave = t >> 6;       // 0..3
    const int tc   = t & 31;       // col quad -> cols 4tc..4tc+3
    const int tg   = t >> 5;       // row group -> rows 4tg..4tg+3
    const int swz  = tc & 7;
    const size_t row0 = (size_t)blockIdx.x * BR;

    // W staging: 16 stripes of 8 rows (1 KB each); wave w stages stripes
    // 4q+w. Lane l -> row 8*stripe + (l>>3), phys chunk l&7, so the
    // logical chunk is (l&7) ^ ((row>>2)&7)  [inverse of read swizzle].
    const float* wsrc[4];
    int ldst[4];
    #pragma unroll
    for (int q = 0; q < 4; ++q) {
        const int stripe = 4 * q + wave;            // 0..15
        const int srow   = 8 * stripe + (lane >> 3);
        const int cj     = (lane & 7) ^ ((srow >> 2) & 7);
        wsrc[q] = W + (size_t)srow * D_DIM + 4 * cj;
        ldst[q] = stripe * 256;    // float offset of this 1 KB stripe
    }

    // X row pointers (advance by BD per chunk -> in-loop offsets are imm)
    const float* xrow[4];
    #pragma unroll
    for (int rr = 0; rr < 4; ++rr)
        xrow[rr] = X + (row0 + 4 * tg + rr) * D_DIM;

    float acc[4][4];   // [ci][rr]
    #pragma unroll
    for (int ci = 0; ci < 4; ++ci)
        #pragma unroll
        for (int rr = 0; rr < 4; ++rr) acc[ci][rr] = 0.0f;

    // prologue: stage chunk 0 into buffer 0
    #pragma unroll
    for (int q = 0; q < 4; ++q)
        gload_lds16(wsrc[q], &wsh[0][ldst[q]]);
    #pragma unroll
    for (int q = 0; q < 4; ++q) wsrc[q] += BD;

    for (int ch = 0; ch < NCHUNK; ++ch) {
        __syncthreads();           // stage(ch) landed; prev buf reads done
        const int buf = ch & 1;
        const float* wb = &wsh[buf][0];

        float4 xf[2][4];
        #pragma unroll
        for (int rr = 0; rr < 4; ++rr)         // X for jp=0
            xf[0][rr] = *(const float4*)(xrow[rr]);

        if (ch + 1 < NCHUNK) {     // stage next chunk into other buffer
            #pragma unroll
            for (int q = 0; q < 4; ++q)
                gload_lds16(wsrc[q], &wsh[buf ^ 1][ldst[q]]);
            #pragma unroll
            for (int q = 0; q < 4; ++q) wsrc[q] += BD;
        }

        #pragma unroll
        for (int jp = 0; jp < 8; ++jp) {
            if (jp + 1 < 8) {      // X prefetch, depth 1 (imm offsets)
                #pragma unroll
                for (int rr = 0; rr < 4; ++rr)
                    xf[(jp + 1) & 1][rr] =
                        *(const float4*)(xrow[rr] + 4 * (jp + 1));
            }
            float4 wf[4];          // W at use; compiler hoists addrs
            #pragma unroll
            for (int ci = 0; ci < 4; ++ci)
                wf[ci] = *(const float4*)
                    &wb[(4 * tc + ci) * BD + ((jp ^ swz) << 2)];
            // d = ch*32 + jp*4 + e, ascending (bit-exact chain order)
            #pragma unroll
            for (int e = 0; e < 4; ++e)
                #pragma unroll
                for (int rr = 0; rr < 4; ++rr) {
                    const float xv = ((const float*)&xf[jp & 1][rr])[e];
                    #pragma unroll
                    for (int ci = 0; ci < 4; ++ci)
                        acc[ci][rr] = __fmaf_rn(
                            xv, ((const float*)&wf[ci])[e], acc[ci][rr]);
                }
        }
        #pragma unroll
        for (int rr = 0; rr < 4; ++rr) xrow[rr] += BD;
    }

    // ---- FWHT, fp32, ascending column bits. col = 4*tc + ci ----
    // bits 0,1 live in ci (register butterflies, FIRST)
    #pragma unroll
    for (int rr = 0; rr < 4; ++rr) {
        const float a0 = acc[0][rr], a1 = acc[1][rr];
        const float a2 = acc[2][rr], a3 = acc[3][rr];
        const float b0 = __fadd_rn(a0, a1), b1 = __fsub_rn(a0, a1);   // bit 0
        const float b2 = __fadd_rn(a2, a3), b3 = __fsub_rn(a2, a3);
        acc[0][rr] = __fadd_rn(b0, b2);                                // bit 1
        acc[1][rr] = __fadd_rn(b1, b3);
        acc[2][rr] = __fsub_rn(b0, b2);
        acc[3][rr] = __fsub_rn(b1, b3);
    }
    // bits 2..6 live in tc = lane bits 0..4 (same tg on both shuffle ends)
    #pragma unroll
    for (int h = 1; h <= 16; h <<= 1) {
        const bool up = (tc & h) != 0;
        #pragma unroll
        for (int ci = 0; ci < 4; ++ci)
            #pragma unroll
            for (int rr = 0; rr < 4; ++rr) {
                const float mine  = acc[ci][rr];
                const float other = __shfl_xor(mine, h, 64);
                acc[ci][rr] = up ? __fsub_rn(other, mine)
                                 : __fadd_rn(mine, other);
            }
    }

    // sign + coalesced float4 store
    #pragma unroll
    for (int rr = 0; rr < 4; ++rr) {
        float4 v;
        v.x = (acc[0][rr] > 0.0f) ? 1.0f : 0.0f;
        v.y = (acc[1][rr] > 0.0f) ? 1.0f : 0.0f;
        v.z = (acc[2][rr] > 0.0f) ? 1.0f : 0.0f;
        v.w = (acc[3][rr] > 0.0f) ? 1.0f : 0.0f;
        *(float4*)(out + (row0 + 4 * tg + rr) * M_DIM + 4 * tc) = v;
    }
}

extern "C" void kernel_launch(void* const* d_in, const int* in_sizes, int n_in,
                              void* d_out, int out_size, void* d_ws, size_t ws_size,
                              hipStream_t stream) {
    const float* x = (const float*)d_in[0];
    const float* W = (const float*)d_in[1];
    float* out = (float*)d_out;
    const int nrows = out_size / M_DIM;   // 32768

    hipLaunchKernelGGL(rewa_kernel, dim3(nrows / BR), dim3(256), 0, stream,
                       x, W, out);
}